// Round 2
// baseline (6081.096 us; speedup 1.0000x reference)
//
#include <hip/hip_runtime.h>

#define TT 20
#define HH 20

__device__ __forceinline__ float fast_sigmoid(float x) {
    // 1/(1+exp(-x)) = rcp(1 + exp2(-x*log2(e)))
    float e = __builtin_amdgcn_exp2f(-1.44269504f * x);
    return __builtin_amdgcn_rcpf(1.0f + e);
}

__device__ __forceinline__ float fast_tanh(float x) {
    // tanh(x) = 1 - 2/(exp(2x)+1); saturates to +/-1 without NaN at |x| large
    float e = __builtin_amdgcn_exp2f(2.88539008f * x);
    return 1.0f - 2.0f * __builtin_amdgcn_rcpf(e + 1.0f);
}

// Weights are wave-uniform: all indices into w_ih/w_hh/b_*/w_fc are
// compile-time/loop-uniform, pointers are const __restrict__, so the
// compiler can prove noclobber and emit s_load_* (SMEM) — weights live in
// SGPRs and every inner op is v_fmac_f32 v, s, v. No LDS at all.
__global__ __launch_bounds__(256, 4)
void coord_lstm_kernel(const float* __restrict__ grads,
                       const float* __restrict__ w_ih,
                       const float* __restrict__ w_hh,
                       const float* __restrict__ b_ih,
                       const float* __restrict__ b_hh,
                       const float* __restrict__ w_fc,
                       const float* __restrict__ b_fc,
                       float* __restrict__ out,
                       int N)
{
    const int n = blockIdx.x * 256 + threadIdx.x;
    if (n >= N) return;

    float h[HH], c[HH];
    #pragma unroll
    for (int u = 0; u < HH; ++u) { h[u] = 0.0f; c[u] = 0.0f; }

    float x = grads[n];   // t = 0

    #pragma unroll 1      // keep t-loop rolled: body ~2.2k VALU ops, protect I$
    for (int t = 0; t < TT; ++t) {
        // prefetch next step's input; dependence distance ~ full step body
        const int tn = (t + 1 < TT) ? t + 1 : t;
        const float x_next = grads[(size_t)tn * N + n];

        float hn[HH];
        #pragma unroll
        for (int u = 0; u < HH; ++u) {
            float ai = b_ih[u         ] + b_hh[u         ] + x * w_ih[u         ];
            float af = b_ih[u +     HH] + b_hh[u +     HH] + x * w_ih[u +     HH];
            float ag = b_ih[u + 2 * HH] + b_hh[u + 2 * HH] + x * w_ih[u + 2 * HH];
            float ao = b_ih[u + 3 * HH] + b_hh[u + 3 * HH] + x * w_ih[u + 3 * HH];
            #pragma unroll
            for (int j = 0; j < HH; ++j) {
                const float hj = h[j];
                ai += hj * w_hh[(u         ) * HH + j];
                af += hj * w_hh[(u +     HH) * HH + j];
                ag += hj * w_hh[(u + 2 * HH) * HH + j];
                ao += hj * w_hh[(u + 3 * HH) * HH + j];
            }
            const float cn = fast_sigmoid(af) * c[u] + fast_sigmoid(ai) * fast_tanh(ag);
            c[u] = cn;
            hn[u] = fast_sigmoid(ao) * fast_tanh(cn);
        }
        float o = b_fc[0];
        #pragma unroll
        for (int u = 0; u < HH; ++u) {
            o += hn[u] * w_fc[u];
            h[u] = hn[u];
        }
        out[(size_t)t * N + n] = o;
        x = x_next;
    }
}

extern "C" void kernel_launch(void* const* d_in, const int* in_sizes, int n_in,
                              void* d_out, int out_size, void* d_ws, size_t ws_size,
                              hipStream_t stream) {
    const float* grads = (const float*)d_in[0];
    const float* w_ih  = (const float*)d_in[1];
    const float* w_hh  = (const float*)d_in[2];
    const float* b_ih  = (const float*)d_in[3];
    const float* b_hh  = (const float*)d_in[4];
    const float* w_fc  = (const float*)d_in[5];
    const float* b_fc  = (const float*)d_in[6];
    float* out = (float*)d_out;

    const int N = in_sizes[0] / TT;   // grads is (T, N)
    const int grid = (N + 255) / 256;
    coord_lstm_kernel<<<grid, 256, 0, stream>>>(grads, w_ih, w_hh, b_ih, b_hh,
                                                w_fc, b_fc, out, N);
}